// Round 9
// baseline (1068.164 us; speedup 1.0000x reference)
//
#include <hip/hip_runtime.h>
#include <stdint.h>

#define D_IN 2048
#define HID  16384
#define NTOK 8192
#define KSEL 64
#define CANDCAP 192
#define PSEG 20
#define EPSB 0.008f
#define TAU 1.3f

typedef __attribute__((ext_vector_type(8))) short bf16x8;
typedef __attribute__((ext_vector_type(4))) float f32x4;
typedef __attribute__((ext_vector_type(16))) float f32x16;
typedef unsigned int u32;
typedef unsigned short u16;
typedef unsigned char u8;

__device__ __forceinline__ u16 f2bf(float f){
  u32 b = __builtin_bit_cast(u32, f);
  return (u16)((b + 0x7FFFu + ((b>>16)&1u)) >> 16);
}
__device__ __forceinline__ float bf2f(u16 u){
  return __builtin_bit_cast(float, (u32)u << 16);
}
__device__ __forceinline__ u16 f2h(float f){
  return __builtin_bit_cast(u16, (_Float16)f);
}
__device__ __forceinline__ float h2f(u16 u){
  return (float)__builtin_bit_cast(_Float16, u);
}
// monotone order-key for IEEE sign-magnitude 16-bit patterns
__device__ __forceinline__ u16 key_of(u16 u){
  return (u & 0x8000u) ? (u16)(~u) : (u16)(u | 0x8000u);
}
__device__ __forceinline__ u16 kinv(u32 k){
  return (k & 0x8000u) ? (u16)(k & 0x7FFFu) : (u16)(~k);
}
__device__ __forceinline__ u32 fkey16(float f){ return (u32)key_of(f2h(f)); }

// ---------------- convert: x-mean -> bf16, enc_w -> bf16 ----------------
__global__ __launch_bounds__(256) void k_convert_x(const float* __restrict__ x,
                                                   const float* __restrict__ mean,
                                                   u16* __restrict__ xb){
  long i = (long)blockIdx.x*256 + threadIdx.x;
  long base = i*8;
  int d = (int)(base & (D_IN-1));
  float4 a = *(const float4*)(x+base);
  float4 b = *(const float4*)(x+base+4);
  float4 m0 = *(const float4*)(mean+d);
  float4 m1 = *(const float4*)(mean+d+4);
  uint4 ov;
  ov.x = (u32)f2bf(a.x-m0.x) | ((u32)f2bf(a.y-m0.y)<<16);
  ov.y = (u32)f2bf(a.z-m0.z) | ((u32)f2bf(a.w-m0.w)<<16);
  ov.z = (u32)f2bf(b.x-m1.x) | ((u32)f2bf(b.y-m1.y)<<16);
  ov.w = (u32)f2bf(b.z-m1.z) | ((u32)f2bf(b.w-m1.w)<<16);
  *(uint4*)(xb+base) = ov;
}

__global__ __launch_bounds__(256) void k_convert_w(const float* __restrict__ wsrc,
                                                   u16* __restrict__ wb){
  long i = (long)blockIdx.x*256 + threadIdx.x;
  long base = i*8;
  float4 a = *(const float4*)(wsrc+base);
  float4 b = *(const float4*)(wsrc+base+4);
  uint4 ov;
  ov.x = (u32)f2bf(a.x) | ((u32)f2bf(a.y)<<16);
  ov.y = (u32)f2bf(a.z) | ((u32)f2bf(a.w)<<16);
  ov.z = (u32)f2bf(b.x) | ((u32)f2bf(b.y)<<16);
  ov.w = (u32)f2bf(b.z) | ((u32)f2bf(b.w)<<16);
  *(uint4*)(wb+base) = ov;
}

// ---------------- bf16 GEMM, 256x256 tile, BK=64, 8 waves, counted-vmcnt ----
// r5 barrier/vmcnt skeleton (510us/50.6%) with 32x32x16 MFMA (half the matrix-pipe
// instructions, +15% ceiling). 2 phases/kt, each: vmcnt(4); barrier; 12 ds_read_b128;
// 2 STAGE (4 gloads); setprio(1) 16 MFMA setprio(0).
// A/B frag: row=lane&31, k=(lane>>5)*8+e. C/D: col=lane&31, row=(reg&3)+8*(reg>>2)+4*(lane>>5).
__global__ __launch_bounds__(512, 2) void k_gemm(const u16* __restrict__ A,   // [NTOK, D_IN]
                                                 const u16* __restrict__ B,   // [HID, D_IN]
                                                 const float* __restrict__ bias,
                                                 u32* __restrict__ plist,
                                                 u8*  __restrict__ pcnt8){
  __shared__ u16 lds[65536];   // 128 KiB
  const int t = threadIdx.x, lane = t & 63, w = t >> 6;
  const int wm = w >> 2, wn = w & 3;
  const int l31 = lane & 31, l5 = lane >> 5;

  int wg = blockIdx.x;
  int wgid = (wg & 7)*256 + (wg >> 3);
  int sb = wgid >> 6, wi = wgid & 63;
  int bm = (sb & 3)*8 + (wi & 7);      // 0..31
  int bn = (sb >> 2)*8 + (wi >> 3);    // 0..63
  const u16* aT = A + (size_t)bm*256*D_IN;
  const u16* bT = B + (size_t)bn*256*D_IN;

  int srcOff[2], ldst[2];
  #pragma unroll
  for (int i = 0; i < 2; ++i){
    int sr = i*64 + w*8 + (lane >> 3);
    int u  = (lane & 7) ^ (sr & 7);
    int r  = (sr << 1) | (u >> 2);
    int c8 = (u & 3) * 8;
    srcOff[i] = r*D_IN + c8;
    ldst[i]   = i*4096 + w*512 + lane*8;
  }
  #define STAGE(bufb, ktp, khh, isB) do { \
    const u16* _s = ((isB) ? bT : aT) + (ktp)*64 + (khh)*32; \
    u16* _d = lds + (bufb)*32768 + ((isB)?16384:0) + (khh)*8192; \
    __builtin_amdgcn_global_load_lds( \
      (const __attribute__((address_space(1))) u32*)(_s + srcOff[0]), \
      (__attribute__((address_space(3))) u32*)(_d + ldst[0]), 16, 0, 0); \
    __builtin_amdgcn_global_load_lds( \
      (const __attribute__((address_space(1))) u32*)(_s + srcOff[1]), \
      (__attribute__((address_space(3))) u32*)(_d + ldst[1]), 16, 0, 0); \
  } while(0)

  // swizzled read base for fragment row = (32-block) + l31, chunk c = ks*2 + l5:
  //   u16 idx = (rowblk/2 + l31>>1)*64 + (((((l31&1)<<2) | c) ^ ((l31>>1)&7))*8
  int abase[2], bbase[2];
  #pragma unroll
  for (int ks = 0; ks < 2; ++ks){
    int c = ks*2 + l5;
    int sl = (((((l31 & 1) << 2) | c) ^ ((l31 >> 1) & 7))) * 8;
    abase[ks] = (wm*64 + (l31 >> 1))*64 + sl;            // + fm*1024 + kh*8192 + buf*32768
    bbase[ks] = (wn*32 + (l31 >> 1))*64 + sl + 16384;    // + fn*1024
  }

  f32x16 acc[4][2] = {};

  STAGE(0, 0, 0, 0); STAGE(0, 0, 0, 1); STAGE(0, 0, 1, 0); STAGE(0, 0, 1, 1);

  #pragma unroll 1
  for (int kt = 0; kt < D_IN/64; ++kt){
    const int cur = kt & 1, nxt = cur ^ 1;
    const int ab = cur*32768;
    const bool pre = (kt < D_IN/64 - 1);
    bf16x8 av[4][2], bv[2][2];

    // ---- phase 1: kh0 ----
    asm volatile("s_waitcnt vmcnt(4)" ::: "memory");
    __builtin_amdgcn_s_barrier();
    #pragma unroll
    for (int fm = 0; fm < 4; ++fm)
      #pragma unroll
      for (int ks = 0; ks < 2; ++ks)
        av[fm][ks] = *(const bf16x8*)(lds + ab + abase[ks] + fm*1024);
    #pragma unroll
    for (int fn = 0; fn < 2; ++fn)
      #pragma unroll
      for (int ks = 0; ks < 2; ++ks)
        bv[fn][ks] = *(const bf16x8*)(lds + ab + bbase[ks] + fn*1024);
    if (pre){ STAGE(nxt, kt+1, 0, 0); STAGE(nxt, kt+1, 0, 1); }
    __builtin_amdgcn_s_setprio(1);
    #pragma unroll
    for (int fm = 0; fm < 4; ++fm)
      #pragma unroll
      for (int fn = 0; fn < 2; ++fn)
        #pragma unroll
        for (int ks = 0; ks < 2; ++ks)
          acc[fm][fn] = __builtin_amdgcn_mfma_f32_32x32x16_bf16(av[fm][ks], bv[fn][ks], acc[fm][fn], 0, 0, 0);
    __builtin_amdgcn_s_setprio(0);

    // ---- phase 2: kh1 ----
    if (pre) { asm volatile("s_waitcnt vmcnt(4)" ::: "memory"); }
    else     { asm volatile("s_waitcnt vmcnt(0)" ::: "memory"); }
    __builtin_amdgcn_s_barrier();
    #pragma unroll
    for (int fm = 0; fm < 4; ++fm)
      #pragma unroll
      for (int ks = 0; ks < 2; ++ks)
        av[fm][ks] = *(const bf16x8*)(lds + ab + 8192 + abase[ks] + fm*1024);
    #pragma unroll
    for (int fn = 0; fn < 2; ++fn)
      #pragma unroll
      for (int ks = 0; ks < 2; ++ks)
        bv[fn][ks] = *(const bf16x8*)(lds + ab + 8192 + bbase[ks] + fn*1024);
    if (pre){ STAGE(nxt, kt+1, 1, 0); STAGE(nxt, kt+1, 1, 1); }
    __builtin_amdgcn_s_setprio(1);
    #pragma unroll
    for (int fm = 0; fm < 4; ++fm)
      #pragma unroll
      for (int fn = 0; fn < 2; ++fn)
        #pragma unroll
        for (int ks = 0; ks < 2; ++ks)
          acc[fm][fn] = __builtin_amdgcn_mfma_f32_32x32x16_bf16(av[fm][ks], bv[fn][ks], acc[fm][fn], 0, 0, 0);
    __builtin_amdgcn_s_setprio(0);
  }
  #undef STAGE

  // ---- epilogue: LDS-counter push into owned 20-slot segments ----
  // C/D: col = lane&31, row = (reg&3) + 8*(reg>>2) + 4*(lane>>5)
  __syncthreads();                    // all LDS reads of the main loop done
  u32* cnt = (u32*)lds;               // reuse staging LDS: 256 row counters
  if (t < 256) cnt[t] = 0u;
  __syncthreads();
  #pragma unroll
  for (int fn = 0; fn < 2; ++fn){
    int gc = bn*256 + wn*64 + fn*32 + l31;
    float bvs = bias[gc];
    #pragma unroll
    for (int fm = 0; fm < 4; ++fm){
      int rbase = wm*128 + fm*32 + 4*l5;
      #pragma unroll
      for (int r = 0; r < 16; ++r){
        float v = acc[fm][fn][r] + bvs;
        if (v >= TAU){
          int lrow = rbase + (r & 3) + 8*(r >> 2);
          u32 pos = atomicAdd(&cnt[lrow], 1u);
          if (pos < PSEG){
            size_t row = (size_t)bm*256 + lrow;
            plist[(row*64 + bn)*PSEG + pos] = ((u32)key_of(f2h(v)) << 16) | (u32)gc;
          }
        }
      }
    }
  }
  __syncthreads();
  if (t < 256){
    u32 c = cnt[t]; if (c > PSEG) c = PSEG;
    pcnt8[(size_t)bn*NTOK + bm*256 + t] = (u8)c;   // [bn][row]: 256 consecutive bytes/block
  }
}

// ---------------- select: exact top-64 threshold over pushed candidates ----------------
// One wave per row; lane <-> bn-panel; barrier-free; prefix-sum compaction.
__global__ __launch_bounds__(256) void k_select(const u32* __restrict__ plist,
                                                const u8* __restrict__ pcnt8,
                                                int* __restrict__ cand,
                                                int* __restrict__ scnt_out,
                                                int* __restrict__ acnt_out,
                                                int* __restrict__ tki,
                                                float* __restrict__ tkv){
  int t = threadIdx.x, lane = t & 63, w = t >> 6;
  int row = blockIdx.x*4 + w;
  int cnt = pcnt8[(size_t)lane*NTOK + row];
  const uint4* s4 = (const uint4*)(plist + ((size_t)row*64 + lane)*PSEG);  // 80B, 16B-aligned
  uint4 q0 = s4[0], q1 = s4[1], q2 = s4[2], q3 = s4[3], q4 = s4[4];
  u32 e[PSEG] = { q0.x,q0.y,q0.z,q0.w, q1.x,q1.y,q1.z,q1.w, q2.x,q2.y,q2.z,q2.w,
                  q3.x,q3.y,q3.z,q3.w, q4.x,q4.y,q4.z,q4.w };
  #pragma unroll
  for (int i = 0; i < PSEG; ++i) if (i >= cnt) e[i] = 0u;
  u32 lo = 0, hi = 65536;   // invariant: count(key>=lo) >= 64 > count(key>=hi)
  for (int it = 0; it < 16; ++it){
    u32 mid = (lo + hi) >> 1;
    int c = 0;
    #pragma unroll
    for (int i = 0; i < PSEG; ++i) c += ((e[i] >> 16) >= mid);
    #pragma unroll
    for (int off = 32; off; off >>= 1) c += __shfl_xor(c, off);
    if (c >= KSEL) lo = mid; else hi = mid;
  }
  float T = h2f(kinv(lo));            // exact fp16 64th-largest of noisy z
  u32 khi = fkey16(T + 2.0f*EPSB);
  u32 klo = fkey16(T - 2.0f*EPSB);
  int ns = 0, na = 0;
  #pragma unroll
  for (int i = 0; i < PSEG; ++i){
    u32 k = e[i] >> 16;
    ns += (k >= khi);
    na += (k >= klo) && (k < khi);
  }
  int ps = ns, pa = na;
  #pragma unroll
  for (int off = 1; off < 64; off <<= 1){
    int a1 = __shfl_up(ps, off);
    int a2 = __shfl_up(pa, off);
    if (lane >= off){ ps += a1; pa += a2; }
  }
  int S = __shfl(ps, 63);
  int A = __shfl(pa, 63);
  ps -= ns; pa -= na;    // exclusive
  #pragma unroll
  for (int i = 0; i < PSEG; ++i){
    u32 k = e[i] >> 16; int gc = (int)(e[i] & 0xFFFFu);
    if (k >= khi){                          // surely in top-64
      tki[(size_t)row*KSEL + ps] = gc;
      tkv[(size_t)row*KSEL + ps] = h2f(kinv(k));
      ps++;
    } else if (k >= klo){                   // ambiguous band
      if (pa < CANDCAP) cand[(size_t)row*CANDCAP + pa] = gc;
      pa++;
    }
  }
  if (lane == 63){
    scnt_out[row] = S;
    acnt_out[row] = (A < CANDCAP) ? A : CANDCAP;
  }
}

// ---------------- fp64 refine of ambiguous band, fill slots [S..64) ----------------
__global__ __launch_bounds__(256) void k_refine(const float* __restrict__ x,
                                                const float* __restrict__ mean,
                                                const float* __restrict__ encw,
                                                const float* __restrict__ encb,
                                                const int* __restrict__ cand,
                                                const int* __restrict__ scnt_in,
                                                const int* __restrict__ acnt_in,
                                                int* __restrict__ tki,
                                                float* __restrict__ tkv){
  __shared__ double vals[4][CANDCAP];
  __shared__ int    idxs[4][CANDCAP];
  int t = threadIdx.x, lane = t & 63, w = t >> 6;
  int row = blockIdx.x*4 + w;
  const float* xr = x + (size_t)row*D_IN;
  float4 xv[8];
  #pragma unroll
  for (int e = 0; e < 8; ++e){
    float4 a = *(const float4*)(xr + (lane + 64*e)*4);
    float4 m = *(const float4*)(mean + (lane + 64*e)*4);
    xv[e].x = a.x-m.x; xv[e].y = a.y-m.y; xv[e].z = a.z-m.z; xv[e].w = a.w-m.w;
  }
  int S = scnt_in[row];
  int A = acnt_in[row];
  int need = KSEL - S;
  for (int i = lane; i < A; i += 64) idxs[w][i] = cand[(size_t)row*CANDCAP + i];
  int c = 0;
  for (; c + 2 <= A; c += 2){           // 2-way ILP on the dot products
    int h0 = idxs[w][c], h1 = idxs[w][c+1];
    const float4* w0 = (const float4*)(encw + (size_t)h0*D_IN);
    const float4* w1 = (const float4*)(encw + (size_t)h1*D_IN);
    double s0 = 0.0, s1 = 0.0;
    #pragma unroll
    for (int e = 0; e < 8; ++e){
      float4 f0 = w0[lane + 64*e];
      float4 f1 = w1[lane + 64*e];
      s0 = fma((double)xv[e].x,(double)f0.x,s0); s1 = fma((double)xv[e].x,(double)f1.x,s1);
      s0 = fma((double)xv[e].y,(double)f0.y,s0); s1 = fma((double)xv[e].y,(double)f1.y,s1);
      s0 = fma((double)xv[e].z,(double)f0.z,s0); s1 = fma((double)xv[e].z,(double)f1.z,s1);
      s0 = fma((double)xv[e].w,(double)f0.w,s0); s1 = fma((double)xv[e].w,(double)f1.w,s1);
    }
    #pragma unroll
    for (int off = 32; off; off >>= 1){ s0 += __shfl_down(s0, off); s1 += __shfl_down(s1, off); }
    if (lane == 0){ vals[w][c] = s0 + (double)encb[h0]; vals[w][c+1] = s1 + (double)encb[h1]; }
  }
  if (c < A){
    int h0 = idxs[w][c];
    const float4* w0 = (const float4*)(encw + (size_t)h0*D_IN);
    double s0 = 0.0;
    #pragma unroll
    for (int e = 0; e < 8; ++e){
      float4 f0 = w0[lane + 64*e];
      s0 = fma((double)xv[e].x,(double)f0.x,s0);
      s0 = fma((double)xv[e].y,(double)f0.y,s0);
      s0 = fma((double)xv[e].z,(double)f0.z,s0);
      s0 = fma((double)xv[e].w,(double)f0.w,s0);
    }
    #pragma unroll
    for (int off = 32; off; off >>= 1) s0 += __shfl_down(s0, off);
    if (lane == 0) vals[w][c] = s0 + (double)encb[h0];
  }
  for (int i = lane; i < A; i += 64){
    double v = vals[w][i]; int h = idxs[w][i];
    int rank = 0;
    for (int j = 0; j < A; ++j){
      double vj = vals[w][j];
      rank += (vj > v) || (vj == v && idxs[w][j] < h);
    }
    if (rank < need){
      tki[(size_t)row*KSEL + S + rank] = h;
      tkv[(size_t)row*KSEL + S + rank] = (float)v;
    }
  }
}

// ---------------- dec_w transpose [2048,16384] fp32 -> [16384,2048] bf16 ----------------
__global__ __launch_bounds__(256) void k_transpose(const float* __restrict__ src,
                                                   u16* __restrict__ dst){
  __shared__ u16 tile[32][34];   // stride 17 words, coprime with 32 banks
  int tx = threadIdx.x & 31, ty = threadIdx.x >> 5;
  int bh = blockIdx.x;
  int bd = blockIdx.y;
  #pragma unroll
  for (int i = 0; i < 4; ++i){
    int d = bd*32 + ty + i*8;
    tile[ty + i*8][tx] = f2bf(src[(size_t)d*HID + bh*32 + tx]);
  }
  __syncthreads();
  #pragma unroll
  for (int i = 0; i < 4; ++i){
    int h = bh*32 + ty + i*8;
    dst[(size_t)h*D_IN + bd*32 + tx] = tile[tx][ty + i*8];
  }
}

// ---------------- sparse decode (bf16 weights), 8-way batched gather ----------------
__global__ __launch_bounds__(256) void k_decode(const u16* __restrict__ wT,
                                                const int* __restrict__ tki,
                                                const float* __restrict__ tkv,
                                                const float* __restrict__ decb,
                                                const float* __restrict__ mean,
                                                float* __restrict__ out){
  __shared__ int hk[KSEL];
  __shared__ float vk[KSEL];
  int n = blockIdx.x, t = threadIdx.x;
  if (t < KSEL){ hk[t] = tki[(size_t)n*KSEL + t]; vk[t] = tkv[(size_t)n*KSEL + t]; }
  __syncthreads();
  int d0 = t*8;
  float a[8] = {0,0,0,0,0,0,0,0};
  #pragma unroll 1
  for (int k = 0; k < KSEL; k += 8){
    bf16x8 w0 = *(const bf16x8*)(wT + (size_t)hk[k  ]*D_IN + d0);
    bf16x8 w1 = *(const bf16x8*)(wT + (size_t)hk[k+1]*D_IN + d0);
    bf16x8 w2 = *(const bf16x8*)(wT + (size_t)hk[k+2]*D_IN + d0);
    bf16x8 w3 = *(const bf16x8*)(wT + (size_t)hk[k+3]*D_IN + d0);
    bf16x8 w4 = *(const bf16x8*)(wT + (size_t)hk[k+4]*D_IN + d0);
    bf16x8 w5 = *(const bf16x8*)(wT + (size_t)hk[k+5]*D_IN + d0);
    bf16x8 w6 = *(const bf16x8*)(wT + (size_t)hk[k+6]*D_IN + d0);
    bf16x8 w7 = *(const bf16x8*)(wT + (size_t)hk[k+7]*D_IN + d0);
    float v0 = vk[k], v1 = vk[k+1], v2 = vk[k+2], v3 = vk[k+3];
    float v4 = vk[k+4], v5 = vk[k+5], v6 = vk[k+6], v7 = vk[k+7];
    #pragma unroll
    for (int j = 0; j < 8; ++j){
      a[j] = fmaf(v0, bf2f((u16)w0[j]), a[j]);
      a[j] = fmaf(v1, bf2f((u16)w1[j]), a[j]);
      a[j] = fmaf(v2, bf2f((u16)w2[j]), a[j]);
      a[j] = fmaf(v3, bf2f((u16)w3[j]), a[j]);
      a[j] = fmaf(v4, bf2f((u16)w4[j]), a[j]);
      a[j] = fmaf(v5, bf2f((u16)w5[j]), a[j]);
      a[j] = fmaf(v6, bf2f((u16)w6[j]), a[j]);
      a[j] = fmaf(v7, bf2f((u16)w7[j]), a[j]);
    }
  }
  float4 b0 = *(const float4*)(decb+d0);
  float4 b1 = *(const float4*)(decb+d0+4);
  float4 m0 = *(const float4*)(mean+d0);
  float4 m1 = *(const float4*)(mean+d0+4);
  float4 o0 = { a[0]+b0.x+m0.x, a[1]+b0.y+m0.y, a[2]+b0.z+m0.z, a[3]+b0.w+m0.w };
  float4 o1 = { a[4]+b1.x+m1.x, a[5]+b1.y+m1.y, a[6]+b1.z+m1.z, a[7]+b1.w+m1.w };
  *(float4*)(out + (size_t)n*D_IN + d0)     = o0;
  *(float4*)(out + (size_t)n*D_IN + d0 + 4) = o1;
}

// ---------------- workspace layout (bytes) ----------------
#define OFF_XB    ((size_t)0)                 // 33,554,432   x bf16
#define OFF_WB    ((size_t)33554432)          // 67,108,864   enc_w bf16
#define OFF_PLIST ((size_t)100663296)         // 41,943,040   8192*64*20 u32 segments
#define OFF_PCNT8 ((size_t)142606336)         // 524,288      per-(bn,row) counts
#define OFF_CAND  ((size_t)143130624)         // 6,291,456    ambig idx
#define OFF_SCNT  ((size_t)149422080)         // 32,768
#define OFF_ACNT  ((size_t)149454848)         // 32,768
#define OFF_TKI   ((size_t)149487616)         // 2,097,152
#define OFF_TKV   ((size_t)151584768)         // 2,097,152
#define OFF_WT    ((size_t)153681920)         // 67,108,864   dec_wT bf16
// total: 220,790,784 bytes

extern "C" void kernel_launch(void* const* d_in, const int* in_sizes, int n_in,
                              void* d_out, int out_size, void* d_ws, size_t ws_size,
                              hipStream_t stream) {
  const float* x     = (const float*)d_in[0];
  const float* enc_w = (const float*)d_in[1];
  const float* enc_b = (const float*)d_in[2];
  const float* dec_w = (const float*)d_in[3];
  const float* dec_b = (const float*)d_in[4];
  const float* mean  = (const float*)d_in[5];
  float* out = (float*)d_out;
  char* ws = (char*)d_ws;

  u16* xb    = (u16*)(ws + OFF_XB);
  u16* wb    = (u16*)(ws + OFF_WB);
  u32* plist = (u32*)(ws + OFF_PLIST);
  u8*  pcnt8 = (u8*)(ws + OFF_PCNT8);
  int* cand  = (int*)(ws + OFF_CAND);
  int* scnt  = (int*)(ws + OFF_SCNT);
  int* acnt  = (int*)(ws + OFF_ACNT);
  int* tki   = (int*)(ws + OFF_TKI);
  float* tkv = (float*)(ws + OFF_TKV);
  u16* wT    = (u16*)(ws + OFF_WT);

  k_convert_x<<<NTOK*D_IN/8/256, 256, 0, stream>>>(x, mean, xb);
  k_convert_w<<<(size_t)HID*D_IN/8/256, 256, 0, stream>>>(enc_w, wb);
  k_gemm<<<(NTOK/256)*(HID/256), 512, 0, stream>>>(xb, wb, enc_b, plist, pcnt8);
  k_select<<<NTOK/4, 256, 0, stream>>>(plist, pcnt8, cand, scnt, acnt, tki, tkv);
  k_refine<<<NTOK/4, 256, 0, stream>>>(x, mean, enc_w, enc_b, cand, scnt, acnt, tki, tkv);
  k_transpose<<<dim3(HID/32, D_IN/32), 256, 0, stream>>>(dec_w, wT);
  k_decode<<<NTOK, 256, 0, stream>>>(wT, tki, tkv, dec_b, mean, out);
}

// Round 10
// 998.537 us; speedup vs baseline: 1.0697x; 1.0697x over previous
//
#include <hip/hip_runtime.h>
#include <stdint.h>

#define D_IN 2048
#define HID  16384
#define NTOK 8192
#define KSEL 64
#define CANDCAP 192
#define PSEG 20
#define EPSB 0.008f
#define TAU 1.3f

typedef __attribute__((ext_vector_type(8))) short bf16x8;
typedef __attribute__((ext_vector_type(4))) float f32x4;
typedef unsigned int u32;
typedef unsigned short u16;
typedef unsigned char u8;

__device__ __forceinline__ u16 f2bf(float f){
  u32 b = __builtin_bit_cast(u32, f);
  return (u16)((b + 0x7FFFu + ((b>>16)&1u)) >> 16);
}
__device__ __forceinline__ float bf2f(u16 u){
  return __builtin_bit_cast(float, (u32)u << 16);
}
__device__ __forceinline__ u16 f2h(float f){
  return __builtin_bit_cast(u16, (_Float16)f);
}
__device__ __forceinline__ float h2f(u16 u){
  return (float)__builtin_bit_cast(_Float16, u);
}
// monotone order-key for IEEE sign-magnitude 16-bit patterns
__device__ __forceinline__ u16 key_of(u16 u){
  return (u & 0x8000u) ? (u16)(~u) : (u16)(u | 0x8000u);
}
__device__ __forceinline__ u16 kinv(u32 k){
  return (k & 0x8000u) ? (u16)(k & 0x7FFFu) : (u16)(~k);
}
__device__ __forceinline__ u32 fkey16(float f){ return (u32)key_of(f2h(f)); }

// ---------------- convert: x-mean -> bf16, enc_w -> bf16 ----------------
__global__ __launch_bounds__(256) void k_convert_x(const float* __restrict__ x,
                                                   const float* __restrict__ mean,
                                                   u16* __restrict__ xb){
  long i = (long)blockIdx.x*256 + threadIdx.x;
  long base = i*8;
  int d = (int)(base & (D_IN-1));
  float4 a = *(const float4*)(x+base);
  float4 b = *(const float4*)(x+base+4);
  float4 m0 = *(const float4*)(mean+d);
  float4 m1 = *(const float4*)(mean+d+4);
  uint4 ov;
  ov.x = (u32)f2bf(a.x-m0.x) | ((u32)f2bf(a.y-m0.y)<<16);
  ov.y = (u32)f2bf(a.z-m0.z) | ((u32)f2bf(a.w-m0.w)<<16);
  ov.z = (u32)f2bf(b.x-m1.x) | ((u32)f2bf(b.y-m1.y)<<16);
  ov.w = (u32)f2bf(b.z-m1.z) | ((u32)f2bf(b.w-m1.w)<<16);
  *(uint4*)(xb+base) = ov;
}

__global__ __launch_bounds__(256) void k_convert_w(const float* __restrict__ wsrc,
                                                   u16* __restrict__ wb){
  long i = (long)blockIdx.x*256 + threadIdx.x;
  long base = i*8;
  float4 a = *(const float4*)(wsrc+base);
  float4 b = *(const float4*)(wsrc+base+4);
  uint4 ov;
  ov.x = (u32)f2bf(a.x) | ((u32)f2bf(a.y)<<16);
  ov.y = (u32)f2bf(a.z) | ((u32)f2bf(a.w)<<16);
  ov.z = (u32)f2bf(b.x) | ((u32)f2bf(b.y)<<16);
  ov.w = (u32)f2bf(b.z) | ((u32)f2bf(b.w)<<16);
  *(uint4*)(wb+base) = ov;
}

// ---------------- bf16 GEMM, 256x256 tile, BK=64, 8 waves, counted-vmcnt ----
// (r5/r8 schedule, measured 510 us / 50.6% MfmaUtil, twice reproduced)
// Epilogue: deterministic per-(row,bn-panel) 20-slot segments, LDS counters only.
__global__ __launch_bounds__(512, 2) void k_gemm(const u16* __restrict__ A,   // [NTOK, D_IN]
                                                 const u16* __restrict__ B,   // [HID, D_IN]
                                                 const float* __restrict__ bias,
                                                 u32* __restrict__ plist,
                                                 u8*  __restrict__ pcnt8){
  __shared__ u16 lds[65536];   // 128 KiB
  const int t = threadIdx.x, lane = t & 63, w = t >> 6;
  const int wm = w >> 2, wn = w & 3;
  const int l15 = lane & 15, lhi = lane >> 4;

  int wg = blockIdx.x;
  int wgid = (wg & 7)*256 + (wg >> 3);
  int sb = wgid >> 6, wi = wgid & 63;
  int bm = (sb & 3)*8 + (wi & 7);      // 0..31
  int bn = (sb >> 2)*8 + (wi >> 3);    // 0..63
  const u16* aT = A + (size_t)bm*256*D_IN;
  const u16* bT = B + (size_t)bn*256*D_IN;

  int srcOff[2], ldst[2];
  #pragma unroll
  for (int i = 0; i < 2; ++i){
    int sr = i*64 + w*8 + (lane >> 3);
    int u  = (lane & 7) ^ (sr & 7);
    int r  = (sr << 1) | (u >> 2);
    int c8 = (u & 3) * 8;
    srcOff[i] = r*D_IN + c8;
    ldst[i]   = i*4096 + w*512 + lane*8;
  }
  #define STAGE(bufb, ktp, khh, isB) do { \
    const u16* _s = ((isB) ? bT : aT) + (ktp)*64 + (khh)*32; \
    u16* _d = lds + (bufb)*32768 + ((isB)?16384:0) + (khh)*8192; \
    __builtin_amdgcn_global_load_lds( \
      (const __attribute__((address_space(1))) u32*)(_s + srcOff[0]), \
      (__attribute__((address_space(3))) u32*)(_d + ldst[0]), 16, 0, 0); \
    __builtin_amdgcn_global_load_lds( \
      (const __attribute__((address_space(1))) u32*)(_s + srcOff[1]), \
      (__attribute__((address_space(3))) u32*)(_d + ldst[1]), 16, 0, 0); \
  } while(0)

  const int slot = ((((l15 & 1) << 2) | lhi) ^ (l15 >> 1)) * 8;
  const int aoff = (wm*64 + (l15 >> 1))*64 + slot;
  const int boff = (wn*32 + (l15 >> 1))*64 + slot + 16384;

  f32x4 acc[8][4] = {};

  STAGE(0, 0, 0, 0); STAGE(0, 0, 0, 1); STAGE(0, 0, 1, 0); STAGE(0, 0, 1, 1);

  #pragma unroll 1
  for (int kt = 0; kt < D_IN/64; ++kt){
    const int cur = kt & 1, nxt = cur ^ 1;
    const int ab = cur*32768;
    const bool pre = (kt < D_IN/64 - 1);
    bf16x8 av[4], bv[4];

    asm volatile("s_waitcnt vmcnt(4)" ::: "memory");
    __builtin_amdgcn_s_barrier();
    #pragma unroll
    for (int fm = 0; fm < 4; ++fm) av[fm] = *(const bf16x8*)(lds + ab + aoff + fm*512);
    #pragma unroll
    for (int fn = 0; fn < 4; ++fn) bv[fn] = *(const bf16x8*)(lds + ab + boff + fn*512);
    if (pre) STAGE(nxt, kt+1, 0, 0);
    __builtin_amdgcn_s_setprio(1);
    #pragma unroll
    for (int fm = 0; fm < 4; ++fm)
      #pragma unroll
      for (int fn = 0; fn < 4; ++fn)
        acc[fm][fn] = __builtin_amdgcn_mfma_f32_16x16x32_bf16(av[fm], bv[fn], acc[fm][fn], 0, 0, 0);
    __builtin_amdgcn_s_setprio(0);

    #pragma unroll
    for (int fm = 0; fm < 4; ++fm) av[fm] = *(const bf16x8*)(lds + ab + aoff + (fm+4)*512);
    if (pre) STAGE(nxt, kt+1, 0, 1);
    __builtin_amdgcn_s_setprio(1);
    #pragma unroll
    for (int fm = 0; fm < 4; ++fm)
      #pragma unroll
      for (int fn = 0; fn < 4; ++fn)
        acc[fm+4][fn] = __builtin_amdgcn_mfma_f32_16x16x32_bf16(av[fm], bv[fn], acc[fm+4][fn], 0, 0, 0);
    __builtin_amdgcn_s_setprio(0);

    if (pre) { asm volatile("s_waitcnt vmcnt(4)" ::: "memory"); }
    else     { asm volatile("s_waitcnt vmcnt(0)" ::: "memory"); }
    __builtin_amdgcn_s_barrier();
    #pragma unroll
    for (int fm = 0; fm < 4; ++fm) av[fm] = *(const bf16x8*)(lds + ab + 8192 + aoff + fm*512);
    #pragma unroll
    for (int fn = 0; fn < 4; ++fn) bv[fn] = *(const bf16x8*)(lds + ab + 8192 + boff + fn*512);
    if (pre) STAGE(nxt, kt+1, 1, 0);
    __builtin_amdgcn_s_setprio(1);
    #pragma unroll
    for (int fm = 0; fm < 4; ++fm)
      #pragma unroll
      for (int fn = 0; fn < 4; ++fn)
        acc[fm][fn] = __builtin_amdgcn_mfma_f32_16x16x32_bf16(av[fm], bv[fn], acc[fm][fn], 0, 0, 0);
    __builtin_amdgcn_s_setprio(0);

    #pragma unroll
    for (int fm = 0; fm < 4; ++fm) av[fm] = *(const bf16x8*)(lds + ab + 8192 + aoff + (fm+4)*512);
    if (pre) STAGE(nxt, kt+1, 1, 1);
    __builtin_amdgcn_s_setprio(1);
    #pragma unroll
    for (int fm = 0; fm < 4; ++fm)
      #pragma unroll
      for (int fn = 0; fn < 4; ++fn)
        acc[fm+4][fn] = __builtin_amdgcn_mfma_f32_16x16x32_bf16(av[fm], bv[fn], acc[fm+4][fn], 0, 0, 0);
    __builtin_amdgcn_s_setprio(0);
  }
  #undef STAGE

  // ---- epilogue: LDS-counter push into owned 20-slot segments ----
  __syncthreads();                    // all LDS reads of the main loop done
  u32* cnt = (u32*)lds;               // reuse staging LDS: 256 row counters
  if (t < 256) cnt[t] = 0u;
  __syncthreads();
  #pragma unroll
  for (int fn = 0; fn < 4; ++fn){
    int gc = bn*256 + wn*64 + fn*16 + l15;
    float bvs = bias[gc];
    #pragma unroll
    for (int fm = 0; fm < 8; ++fm){
      int lrow = wm*128 + fm*16 + lhi*4;
      #pragma unroll
      for (int j = 0; j < 4; ++j){
        float v = acc[fm][fn][j] + bvs;
        if (v >= TAU){
          u32 pos = atomicAdd(&cnt[lrow + j], 1u);
          if (pos < PSEG){
            size_t row = (size_t)bm*256 + lrow + j;
            plist[(row*64 + bn)*PSEG + pos] = ((u32)key_of(f2h(v)) << 16) | (u32)gc;
          }
        }
      }
    }
  }
  __syncthreads();
  if (t < 256){
    u32 c = cnt[t]; if (c > PSEG) c = PSEG;
    pcnt8[(size_t)bn*NTOK + bm*256 + t] = (u8)c;   // [bn][row]: 256 consecutive bytes/block
  }
}

// ---------------- select: exact top-64 threshold over pushed candidates ----------------
// One wave per row; lane <-> bn-panel; barrier-free; prefix-sum compaction.
__global__ __launch_bounds__(256) void k_select(const u32* __restrict__ plist,
                                                const u8* __restrict__ pcnt8,
                                                int* __restrict__ cand,
                                                int* __restrict__ scnt_out,
                                                int* __restrict__ acnt_out,
                                                int* __restrict__ tki,
                                                float* __restrict__ tkv){
  int t = threadIdx.x, lane = t & 63, w = t >> 6;
  int row = blockIdx.x*4 + w;
  int cnt = pcnt8[(size_t)lane*NTOK + row];
  const uint4* s4 = (const uint4*)(plist + ((size_t)row*64 + lane)*PSEG);  // 80B, 16B-aligned
  uint4 q0 = s4[0], q1 = s4[1], q2 = s4[2], q3 = s4[3], q4 = s4[4];
  u32 e[PSEG] = { q0.x,q0.y,q0.z,q0.w, q1.x,q1.y,q1.z,q1.w, q2.x,q2.y,q2.z,q2.w,
                  q3.x,q3.y,q3.z,q3.w, q4.x,q4.y,q4.z,q4.w };
  #pragma unroll
  for (int i = 0; i < PSEG; ++i) if (i >= cnt) e[i] = 0u;
  u32 lo = 0, hi = 65536;   // invariant: count(key>=lo) >= 64 > count(key>=hi)
  for (int it = 0; it < 16; ++it){
    u32 mid = (lo + hi) >> 1;
    int c = 0;
    #pragma unroll
    for (int i = 0; i < PSEG; ++i) c += ((e[i] >> 16) >= mid);
    #pragma unroll
    for (int off = 32; off; off >>= 1) c += __shfl_xor(c, off);
    if (c >= KSEL) lo = mid; else hi = mid;
  }
  float T = h2f(kinv(lo));            // exact fp16 64th-largest of noisy z
  u32 khi = fkey16(T + 2.0f*EPSB);
  u32 klo = fkey16(T - 2.0f*EPSB);
  int ns = 0, na = 0;
  #pragma unroll
  for (int i = 0; i < PSEG; ++i){
    u32 k = e[i] >> 16;
    ns += (k >= khi);
    na += (k >= klo) && (k < khi);
  }
  int ps = ns, pa = na;
  #pragma unroll
  for (int off = 1; off < 64; off <<= 1){
    int a1 = __shfl_up(ps, off);
    int a2 = __shfl_up(pa, off);
    if (lane >= off){ ps += a1; pa += a2; }
  }
  int S = __shfl(ps, 63);
  int A = __shfl(pa, 63);
  ps -= ns; pa -= na;    // exclusive
  #pragma unroll
  for (int i = 0; i < PSEG; ++i){
    u32 k = e[i] >> 16; int gc = (int)(e[i] & 0xFFFFu);
    if (k >= khi){                          // surely in top-64
      tki[(size_t)row*KSEL + ps] = gc;
      tkv[(size_t)row*KSEL + ps] = h2f(kinv(k));
      ps++;
    } else if (k >= klo){                   // ambiguous band
      if (pa < CANDCAP) cand[(size_t)row*CANDCAP + pa] = gc;
      pa++;
    }
  }
  if (lane == 63){
    scnt_out[row] = S;
    acnt_out[row] = (A < CANDCAP) ? A : CANDCAP;
  }
}

// ---------------- fp64 refine of ambiguous band, fill slots [S..64) ----------------
__global__ __launch_bounds__(256) void k_refine(const float* __restrict__ x,
                                                const float* __restrict__ mean,
                                                const float* __restrict__ encw,
                                                const float* __restrict__ encb,
                                                const int* __restrict__ cand,
                                                const int* __restrict__ scnt_in,
                                                const int* __restrict__ acnt_in,
                                                int* __restrict__ tki,
                                                float* __restrict__ tkv){
  __shared__ double vals[4][CANDCAP];
  __shared__ int    idxs[4][CANDCAP];
  int t = threadIdx.x, lane = t & 63, w = t >> 6;
  int row = blockIdx.x*4 + w;
  const float* xr = x + (size_t)row*D_IN;
  float4 xv[8];
  #pragma unroll
  for (int e = 0; e < 8; ++e){
    float4 a = *(const float4*)(xr + (lane + 64*e)*4);
    float4 m = *(const float4*)(mean + (lane + 64*e)*4);
    xv[e].x = a.x-m.x; xv[e].y = a.y-m.y; xv[e].z = a.z-m.z; xv[e].w = a.w-m.w;
  }
  int S = scnt_in[row];
  int A = acnt_in[row];
  int need = KSEL - S;
  for (int i = lane; i < A; i += 64) idxs[w][i] = cand[(size_t)row*CANDCAP + i];
  int c = 0;
  for (; c + 2 <= A; c += 2){           // 2-way ILP on the dot products
    int h0 = idxs[w][c], h1 = idxs[w][c+1];
    const float4* w0 = (const float4*)(encw + (size_t)h0*D_IN);
    const float4* w1 = (const float4*)(encw + (size_t)h1*D_IN);
    double s0 = 0.0, s1 = 0.0;
    #pragma unroll
    for (int e = 0; e < 8; ++e){
      float4 f0 = w0[lane + 64*e];
      float4 f1 = w1[lane + 64*e];
      s0 = fma((double)xv[e].x,(double)f0.x,s0); s1 = fma((double)xv[e].x,(double)f1.x,s1);
      s0 = fma((double)xv[e].y,(double)f0.y,s0); s1 = fma((double)xv[e].y,(double)f1.y,s1);
      s0 = fma((double)xv[e].z,(double)f0.z,s0); s1 = fma((double)xv[e].z,(double)f1.z,s1);
      s0 = fma((double)xv[e].w,(double)f0.w,s0); s1 = fma((double)xv[e].w,(double)f1.w,s1);
    }
    #pragma unroll
    for (int off = 32; off; off >>= 1){ s0 += __shfl_down(s0, off); s1 += __shfl_down(s1, off); }
    if (lane == 0){ vals[w][c] = s0 + (double)encb[h0]; vals[w][c+1] = s1 + (double)encb[h1]; }
  }
  if (c < A){
    int h0 = idxs[w][c];
    const float4* w0 = (const float4*)(encw + (size_t)h0*D_IN);
    double s0 = 0.0;
    #pragma unroll
    for (int e = 0; e < 8; ++e){
      float4 f0 = w0[lane + 64*e];
      s0 = fma((double)xv[e].x,(double)f0.x,s0);
      s0 = fma((double)xv[e].y,(double)f0.y,s0);
      s0 = fma((double)xv[e].z,(double)f0.z,s0);
      s0 = fma((double)xv[e].w,(double)f0.w,s0);
    }
    #pragma unroll
    for (int off = 32; off; off >>= 1) s0 += __shfl_down(s0, off);
    if (lane == 0) vals[w][c] = s0 + (double)encb[h0];
  }
  for (int i = lane; i < A; i += 64){
    double v = vals[w][i]; int h = idxs[w][i];
    int rank = 0;
    for (int j = 0; j < A; ++j){
      double vj = vals[w][j];
      rank += (vj > v) || (vj == v && idxs[w][j] < h);
    }
    if (rank < need){
      tki[(size_t)row*KSEL + S + rank] = h;
      tkv[(size_t)row*KSEL + S + rank] = (float)v;
    }
  }
}

// ---------------- dec_w transpose [2048,16384] fp32 -> [16384,2048] bf16 ----------------
// 32h x 64d tiles: each 8-lane group writes a 128B contiguous run of a wT row.
__global__ __launch_bounds__(256) void k_transpose(const float* __restrict__ src,
                                                   u16* __restrict__ dst){
  __shared__ u16 tile[64][33];
  int tx = threadIdx.x & 31, ty = threadIdx.x >> 5;   // ty 0..7
  int bh = blockIdx.x;  // 0..511 (h tiles of 32)
  int bd = blockIdx.y;  // 0..31  (d tiles of 64)
  #pragma unroll
  for (int i = 0; i < 8; ++i){
    int d = bd*64 + ty + i*8;
    tile[ty + i*8][tx] = f2bf(src[(size_t)d*HID + bh*32 + tx]);
  }
  __syncthreads();
  int hx = threadIdx.x >> 3;    // 0..31: output row within h-tile
  int cg = threadIdx.x & 7;     // 0..7: 16B chunk within 128B run
  uint4 o;
  o.x = (u32)tile[cg*8+0][hx] | ((u32)tile[cg*8+1][hx] << 16);
  o.y = (u32)tile[cg*8+2][hx] | ((u32)tile[cg*8+3][hx] << 16);
  o.z = (u32)tile[cg*8+4][hx] | ((u32)tile[cg*8+5][hx] << 16);
  o.w = (u32)tile[cg*8+6][hx] | ((u32)tile[cg*8+7][hx] << 16);
  *(uint4*)(dst + (size_t)(bh*32 + hx)*D_IN + bd*64 + cg*8) = o;
}

// ---------------- sparse decode (bf16 weights), 8-way batched gather ----------------
__global__ __launch_bounds__(256) void k_decode(const u16* __restrict__ wT,
                                                const int* __restrict__ tki,
                                                const float* __restrict__ tkv,
                                                const float* __restrict__ decb,
                                                const float* __restrict__ mean,
                                                float* __restrict__ out){
  __shared__ int hk[KSEL];
  __shared__ float vk[KSEL];
  int n = blockIdx.x, t = threadIdx.x;
  if (t < KSEL){ hk[t] = tki[(size_t)n*KSEL + t]; vk[t] = tkv[(size_t)n*KSEL + t]; }
  __syncthreads();
  int d0 = t*8;
  float a[8] = {0,0,0,0,0,0,0,0};
  #pragma unroll 1
  for (int k = 0; k < KSEL; k += 8){
    bf16x8 w0 = *(const bf16x8*)(wT + (size_t)hk[k  ]*D_IN + d0);
    bf16x8 w1 = *(const bf16x8*)(wT + (size_t)hk[k+1]*D_IN + d0);
    bf16x8 w2 = *(const bf16x8*)(wT + (size_t)hk[k+2]*D_IN + d0);
    bf16x8 w3 = *(const bf16x8*)(wT + (size_t)hk[k+3]*D_IN + d0);
    bf16x8 w4 = *(const bf16x8*)(wT + (size_t)hk[k+4]*D_IN + d0);
    bf16x8 w5 = *(const bf16x8*)(wT + (size_t)hk[k+5]*D_IN + d0);
    bf16x8 w6 = *(const bf16x8*)(wT + (size_t)hk[k+6]*D_IN + d0);
    bf16x8 w7 = *(const bf16x8*)(wT + (size_t)hk[k+7]*D_IN + d0);
    float v0 = vk[k], v1 = vk[k+1], v2 = vk[k+2], v3 = vk[k+3];
    float v4 = vk[k+4], v5 = vk[k+5], v6 = vk[k+6], v7 = vk[k+7];
    #pragma unroll
    for (int j = 0; j < 8; ++j){
      a[j] = fmaf(v0, bf2f((u16)w0[j]), a[j]);
      a[j] = fmaf(v1, bf2f((u16)w1[j]), a[j]);
      a[j] = fmaf(v2, bf2f((u16)w2[j]), a[j]);
      a[j] = fmaf(v3, bf2f((u16)w3[j]), a[j]);
      a[j] = fmaf(v4, bf2f((u16)w4[j]), a[j]);
      a[j] = fmaf(v5, bf2f((u16)w5[j]), a[j]);
      a[j] = fmaf(v6, bf2f((u16)w6[j]), a[j]);
      a[j] = fmaf(v7, bf2f((u16)w7[j]), a[j]);
    }
  }
  float4 b0 = *(const float4*)(decb+d0);
  float4 b1 = *(const float4*)(decb+d0+4);
  float4 m0 = *(const float4*)(mean+d0);
  float4 m1 = *(const float4*)(mean+d0+4);
  float4 o0 = { a[0]+b0.x+m0.x, a[1]+b0.y+m0.y, a[2]+b0.z+m0.z, a[3]+b0.w+m0.w };
  float4 o1 = { a[4]+b1.x+m1.x, a[5]+b1.y+m1.y, a[6]+b1.z+m1.z, a[7]+b1.w+m1.w };
  *(float4*)(out + (size_t)n*D_IN + d0)     = o0;
  *(float4*)(out + (size_t)n*D_IN + d0 + 4) = o1;
}

// ---------------- workspace layout (bytes) ----------------
#define OFF_XB    ((size_t)0)                 // 33,554,432   x bf16
#define OFF_WB    ((size_t)33554432)          // 67,108,864   enc_w bf16
#define OFF_PLIST ((size_t)100663296)         // 41,943,040   8192*64*20 u32 segments
#define OFF_PCNT8 ((size_t)142606336)         // 524,288      per-(bn,row) counts
#define OFF_CAND  ((size_t)143130624)         // 6,291,456    ambig idx
#define OFF_SCNT  ((size_t)149422080)         // 32,768
#define OFF_ACNT  ((size_t)149454848)         // 32,768
#define OFF_TKI   ((size_t)149487616)         // 2,097,152
#define OFF_TKV   ((size_t)151584768)         // 2,097,152
#define OFF_WT    ((size_t)153681920)         // 67,108,864   dec_wT bf16
// total: 220,790,784 bytes

extern "C" void kernel_launch(void* const* d_in, const int* in_sizes, int n_in,
                              void* d_out, int out_size, void* d_ws, size_t ws_size,
                              hipStream_t stream) {
  const float* x     = (const float*)d_in[0];
  const float* enc_w = (const float*)d_in[1];
  const float* enc_b = (const float*)d_in[2];
  const float* dec_w = (const float*)d_in[3];
  const float* dec_b = (const float*)d_in[4];
  const float* mean  = (const float*)d_in[5];
  float* out = (float*)d_out;
  char* ws = (char*)d_ws;

  u16* xb    = (u16*)(ws + OFF_XB);
  u16* wb    = (u16*)(ws + OFF_WB);
  u32* plist = (u32*)(ws + OFF_PLIST);
  u8*  pcnt8 = (u8*)(ws + OFF_PCNT8);
  int* cand  = (int*)(ws + OFF_CAND);
  int* scnt  = (int*)(ws + OFF_SCNT);
  int* acnt  = (int*)(ws + OFF_ACNT);
  int* tki   = (int*)(ws + OFF_TKI);
  float* tkv = (float*)(ws + OFF_TKV);
  u16* wT    = (u16*)(ws + OFF_WT);

  k_convert_x<<<NTOK*D_IN/8/256, 256, 0, stream>>>(x, mean, xb);
  k_convert_w<<<(size_t)HID*D_IN/8/256, 256, 0, stream>>>(enc_w, wb);
  k_gemm<<<(NTOK/256)*(HID/256), 512, 0, stream>>>(xb, wb, enc_b, plist, pcnt8);
  k_select<<<NTOK/4, 256, 0, stream>>>(plist, pcnt8, cand, scnt, acnt, tki, tkv);
  k_refine<<<NTOK/4, 256, 0, stream>>>(x, mean, enc_w, enc_b, cand, scnt, acnt, tki, tkv);
  k_transpose<<<dim3(HID/32, D_IN/64), 256, 0, stream>>>(dec_w, wT);
  k_decode<<<NTOK, 256, 0, stream>>>(wT, tki, tkv, dec_b, mean, out);
}